// Round 3
// baseline (269.429 us; speedup 1.0000x reference)
//
#include <hip/hip_runtime.h>

#define S_U 256
#define N_IMP 128
#define OUT_STRIDE (4 + N_IMP)
#define TRUNC 0.015625f   // 2/512*4
#define WPB 4             // waves (= rays) per 256-thread block
#define INV127 (1.0f / 127.0f)

// ---- DPP helpers: wave64 inclusive scans, zero LDS ----
// row_shr:N = 0x110+N, row_bcast:15 = 0x142 (row_mask 0xa), row_bcast:31 = 0x143 (row_mask 0xc)
template <int CTRL, int ROWM>
__device__ __forceinline__ float dppf(float identity, float x) {
    return __int_as_float(__builtin_amdgcn_update_dpp(
        __float_as_int(identity), __float_as_int(x), CTRL, ROWM, 0xf, false));
}

__device__ __forceinline__ float wscan_add(float x) {
    x += dppf<0x111, 0xf>(0.f, x);
    x += dppf<0x112, 0xf>(0.f, x);
    x += dppf<0x114, 0xf>(0.f, x);
    x += dppf<0x118, 0xf>(0.f, x);
    x += dppf<0x142, 0xa>(0.f, x);
    x += dppf<0x143, 0xc>(0.f, x);
    return x;   // lane i: sum of lanes 0..i; lane 63 = total
}

__device__ __forceinline__ float wscan_mul(float x) {
    x *= dppf<0x111, 0xf>(1.f, x);
    x *= dppf<0x112, 0xf>(1.f, x);
    x *= dppf<0x114, 0xf>(1.f, x);
    x *= dppf<0x118, 0xf>(1.f, x);
    x *= dppf<0x142, 0xa>(1.f, x);
    x *= dppf<0x143, 0xc>(1.f, x);
    return x;
}

__device__ __forceinline__ int wscan_min(int x) {
    const int I = 0x7fffffff;
    x = min(x, __builtin_amdgcn_update_dpp(I, x, 0x111, 0xf, 0xf, false));
    x = min(x, __builtin_amdgcn_update_dpp(I, x, 0x112, 0xf, 0xf, false));
    x = min(x, __builtin_amdgcn_update_dpp(I, x, 0x114, 0xf, 0xf, false));
    x = min(x, __builtin_amdgcn_update_dpp(I, x, 0x118, 0xf, 0xf, false));
    x = min(x, __builtin_amdgcn_update_dpp(I, x, 0x142, 0xa, 0xf, false));
    x = min(x, __builtin_amdgcn_update_dpp(I, x, 0x143, 0xc, 0xf, false));
    return x;
}

// smallest j in [0,128] with cdf_val <= j*(1/127)  (exact predicate fixup; 128 = "never")
__device__ __forceinline__ int k_of(float c) {
    int k = (int)ceilf(c * 127.0f);
    k = min(max(k, 0), 128);
    if (k > 0 && c <= (float)(k - 1) * INV127) --k;
    else if (k < 128 && !(c <= (float)k * INV127)) ++k;
    return k;
}

__global__ __launch_bounds__(256) void tsdf_render_kernel(
    const float* __restrict__ occ,
    const float* __restrict__ zvals,
    const float* __restrict__ sdf,
    const float* __restrict__ rgbs,
    float* __restrict__ out)
{
    const int lane = threadIdx.x & 63;
    const int wv   = threadIdx.x >> 6;
    const int ray  = blockIdx.x * WPB + wv;

    __shared__ __align__(16) float2 s_pair[WPB][S_U];   // (cdf_i, zmid_i)
    __shared__ int s_below[WPB][N_IMP];

    // ---------------- global loads (all coalesced, issued early) ----------------
    const float4 o4 = ((const float4*)(occ   + (size_t)ray * S_U))[lane];
    const float4 z4 = ((const float4*)(zvals + (size_t)ray * S_U))[lane];
    const float2 sd2 = ((const float2*)(sdf + (size_t)ray * N_IMP))[lane];
    const float2* rg = (const float2*)(rgbs + (size_t)ray * (N_IMP * 3)) + lane * 3;
    const float2 p0 = rg[0];   // r0 g0
    const float2 p1 = rg[1];   // b0 r1
    const float2 p2 = rg[2];   // g1 b1

    // ---------------- occupancy alpha + transmittance (DPP product scan) --------
    float a0 = 1.0f / (1.0f + __expf(-10.0f * o4.x));
    float a1 = 1.0f / (1.0f + __expf(-10.0f * o4.y));
    float a2 = 1.0f / (1.0f + __expf(-10.0f * o4.z));
    float a3 = 1.0f / (1.0f + __expf(-10.0f * o4.w));
    float t0 = 1.0f - a0 + 1e-10f;
    float t1 = 1.0f - a1 + 1e-10f;
    float t2 = 1.0f - a2 + 1e-10f;
    float t3 = 1.0f - a3 + 1e-10f;
    float pp0 = t0, pp1 = pp0 * t1, pp2 = pp1 * t2, pp3 = pp2 * t3;
    float ip = wscan_mul(pp3);
    float pbase = __shfl_up(ip, 1);
    if (lane == 0) pbase = 1.0f;

    float w0 = a0 * pbase;
    float w1 = a1 * pbase * pp0;
    float w2 = a2 * pbase * pp1;
    float w3 = a3 * pbase * pp2;

    // ---------------- CDF over w_u[1..254] + 1e-5 (DPP sum scan) ----------------
    float v0 = (lane > 0)  ? w0 + 1e-5f : 0.0f;   // global idx 4*lane
    float v1 = w1 + 1e-5f;
    float v2 = w2 + 1e-5f;
    float v3 = (lane < 63) ? w3 + 1e-5f : 0.0f;   // idx 255 excluded
    float s0 = v0, s1 = s0 + v1, s2 = s1 + v2, s3 = s2 + v3;
    float is = wscan_add(s3);
    float total = __shfl(is, 63);
    float sbase = __shfl_up(is, 1);
    if (lane == 0) sbase = 0.0f;
    float invt = 1.0f / total;

    float c0 = (sbase + s0) * invt;
    float c1 = (sbase + s1) * invt;
    float c2 = (sbase + s2) * invt;
    float c3 = (sbase + s3) * invt;

    // z midpoints
    float znext = __shfl_down(z4.x, 1);
    float zm0 = 0.5f * (z4.x + z4.y);
    float zm1 = 0.5f * (z4.y + z4.z);
    float zm2 = 0.5f * (z4.z + z4.w);
    float zm3 = 0.5f * (z4.w + znext);   // lane 63: entry 255, never read

    // interleaved (cdf, zmid) pairs -> LDS (2x b128 per lane)
    float2* pr = s_pair[wv];
    *(float4*)&pr[lane * 4 + 0] = make_float4(c0, zm0, c1, zm1);
    *(float4*)&pr[lane * 4 + 2] = make_float4(c2, zm2, c3, zm3);

    // ---------------- scatter: entry i covers samples j in [k_i, k_{i+1}) -------
    int k0 = k_of(c0), k1 = k_of(c1), k2 = k_of(c2), k3 = k_of(c3);
    int kn = __shfl_down(k0, 1);
    if (lane == 63) { k3 = 128; kn = 128; }   // entry 255 doesn't exist; 254 runs to end
    int base = lane * 4;
    int* bel = s_below[wv];
    for (int j = k0; j < k1; ++j) bel[j] = base;
    for (int j = k1; j < k2; ++j) bel[j] = base + 1;
    for (int j = k2; j < k3; ++j) bel[j] = base + 2;
    for (int j = k3; j < kn; ++j) bel[j] = base + 3;

    __builtin_amdgcn_wave_barrier();   // intra-wave LDS write->read ordering pin

    // ---------------- gather + lerp: 2 samples / lane ----------------
    int jj0 = 2 * lane, jj1 = 2 * lane + 1;
    int b0 = bel[jj0], b1 = bel[jj1];
    float2 pb0 = pr[b0];
    float2 pa0 = pr[min(b0 + 1, 254)];
    float2 pb1 = pr[b1];
    float2 pa1 = pr[min(b1 + 1, 254)];

    float u0 = (float)jj0 * INV127;
    float u1 = (float)jj1 * INV127;
    float d0 = pa0.x - pb0.x; d0 = (d0 < 1e-5f) ? 1.0f : d0;
    float d1 = pa1.x - pb1.x; d1 = (d1 < 1e-5f) ? 1.0f : d1;
    float zs0 = pb0.y + ((u0 - pb0.x) / d0) * (pa0.y - pb0.y);
    float zs1 = pb1.y + ((u1 - pb1.x) / d1) * (pa1.y - pb1.y);

    // ---------------- first zero-crossing of sdf (DPP min scan) ----------------
    float sn = __shfl_down(sd2.x, 1);   // sdf[2*lane+2]
    int c = 0x7fffffff;
    if (sd2.x * sd2.y < 0.0f)                 c = 2 * lane;
    else if (lane < 63 && sd2.y * sn < 0.0f)  c = 2 * lane + 1;
    c = wscan_min(c);
    int ci = __shfl(c, 63);
    if (ci == 0x7fffffff) ci = 0;
    float zca = __shfl(zs0, ci >> 1);
    float zcb = __shfl(zs1, ci >> 1);
    float z_min = (ci & 1) ? zcb : zca;

    // ---------------- TSDF alpha + truncation mask ----------------
    float x0 = sd2.x * (1.0f / TRUNC);
    float x1 = sd2.y * (1.0f / TRUNC);
    float al0 = 1.0f / (2.0f + __expf(x0) + __expf(-x0));  // sig(x)*sig(-x)
    float al1 = 1.0f / (2.0f + __expf(x1) + __expf(-x1));
    float zlim = z_min + TRUNC;
    if (!(zs0 < zlim)) al0 = 0.0f;
    if (!(zs1 < zlim)) al1 = 0.0f;

    // ---------------- composite: 5 parallel DPP sum scans ----------------
    float sA = wscan_add(al0 + al1);                    // lane 63: sum(alpha)
    float sR = wscan_add(al0 * p0.x + al1 * p1.y);
    float sG = wscan_add(al0 * p0.y + al1 * p2.x);
    float sB = wscan_add(al0 * p1.x + al1 * p2.y);
    float sD = wscan_add(al0 * zs0  + al1 * zs1);

    float asum = __shfl(sA, 63);
    float inv_s = 1.0f / (asum + 1e-8f);

    float* ob = out + (size_t)ray * OUT_STRIDE;
    ((float2*)(ob + 4))[lane] = make_float2(al0 * inv_s, al1 * inv_s);
    if (lane == 63) {
        float inv63 = 1.0f / (sA + 1e-8f);
        ob[0] = fminf(fmaxf(sR * inv63, 0.0f), 1.0f);
        ob[1] = fminf(fmaxf(sG * inv63, 0.0f), 1.0f);
        ob[2] = fminf(fmaxf(sB * inv63, 0.0f), 1.0f);
        ob[3] = sD * inv63;
    }
}

extern "C" void kernel_launch(void* const* d_in, const int* in_sizes, int n_in,
                              void* d_out, int out_size, void* d_ws, size_t ws_size,
                              hipStream_t stream) {
    const float* occ  = (const float*)d_in[0];
    const float* z    = (const float*)d_in[1];
    const float* sdf  = (const float*)d_in[2];
    const float* rgbs = (const float*)d_in[3];
    float* out = (float*)d_out;
    const int n_rays = in_sizes[0] / S_U;
    hipLaunchKernelGGL(tsdf_render_kernel, dim3(n_rays / WPB), dim3(256), 0, stream,
                       occ, z, sdf, rgbs, out);
}